// Round 13
// baseline (1147.215 us; speedup 1.0000x reference)
//
#include <hip/hip_runtime.h>
#include <math.h>

// Round 13: r12's fused one-dispatch-per-iteration kernel, launched as a
// REGULAR kernel (r9-r12's silent failure: 512-block COOPERATIVE launches
// need 2-blocks/CU co-residency and never ran; error code was discarded).
// Deadlock-free by construction with a regular launch: est blocks (bid>=256)
// only wait on simw blocks (bid<256), which are dispatched first in bid order
// and depend on nothing within the dispatch -> they always complete.
//   simw (bid 0..255, k-split): sims = est.T2g (fp32, DPP reduce) ->
//       W = exp2(c2*sims) (unnormalized softmax: atan2 direction is
//       scale-invariant) into ROTATING slot it -> __threadfence (wbl2 -> LLC)
//       -> hierarchical flag arrival (16 groups x 16, RMW at LLC).
//       At it==NI writes out = sims/4096 instead.
//   est (bid 256..511, d-split): relaxed spin on final counter -> plain
//       float4 reads of slot it (this XCD's L2/L1 never held those lines
//       this dispatch -> must miss to the LLC) -> re/im = W.T1 (DPP reduce)
//       -> est = (re,im)/|z| (no atan2) -> 1 KB est slice store (plain;
//       next dispatch boundary provides coherence — r7/r8-proven).
// Tables bf16 built once. T1[j=2d+cs][k] k-contiguous; T2g[g][j][c]
// j-contiguous.

#define KCODES 1024
#define DIMS   4096
#define BATCH  8
#define JROWS  (DIMS * 2)      // 8192 (cos,sin) rows
#define NITER_MAX 50           // device-side guard handles *nit_p < NITER_MAX

// ws float offsets (~35 MB total)
#define T1_SZF   (JROWS * KCODES / 2)       // bf16: 4,194,304 f32 slots (16 MB)
#define T2_OFF   (T1_SZF)
#define T2_SZF   (T1_SZF)                   // 16 MB
#define EST_OFF  (T2_OFF + T2_SZF)
#define EST_SZ   (JROWS * BATCH)            // est[j][b] f32 (256 KB)
#define W_SZ     (BATCH * KCODES)           // one W slot (32 KB)
#define WROT_OFF (EST_OFF + EST_SZ)         // 50 rotating W slots (1.6 MB)
#define WROT_SZ  (NITER_MAX * W_SZ)
#define FLAG_OFF (WROT_OFF + WROT_SZ)       // group + final counters (u32)

#define NGRP    16
#define GSTRIDE 16                           // 64 B per counter
#define FGRP_SZ (NITER_MAX * NGRP * GSTRIDE) // 12800 u32
#define FFIN_SZ (NITER_MAX * GSTRIDE)        // 800 u32 (64B-padded finals)

#define C2 (0.00244140625f * 1.4426950408889634f)   // (10/4096)*log2(e)

// ---- bf16 helpers ----
__device__ __forceinline__ ushort f2bf(float x) {
  unsigned u = __float_as_uint(x);
  return (ushort)((u + 0x7FFFu + ((u >> 16) & 1u)) >> 16);   // RNE
}
__device__ __forceinline__ float bf2f(ushort u) {
  return __uint_as_float(((unsigned)u) << 16);
}

// ---- DPP wave64 sum: result valid in lane 63 ----
template <int CTRL>
__device__ __forceinline__ float dpp_add(float x) {
  int v = __builtin_amdgcn_update_dpp(0, __float_as_int(x), CTRL, 0xF, 0xF, false);
  return x + __int_as_float(v);
}
__device__ __forceinline__ float wave_sum64(float x) {
  x = dpp_add<0x111>(x);   // row_shr:1
  x = dpp_add<0x112>(x);   // row_shr:2
  x = dpp_add<0x114>(x);   // row_shr:4
  x = dpp_add<0x118>(x);   // row_shr:8
  x = dpp_add<0x142>(x);   // row_bcast:15
  x = dpp_add<0x143>(x);   // row_bcast:31
  return x;                // lane 63 = sum of all 64 lanes
}

// ---- one-time: T1[j][k] build via LDS tile transpose (r7/r8-proven) ----
__global__ __launch_bounds__(256) void k_trig(const float* __restrict__ cb,
                                              float* __restrict__ ws) {
  __shared__ float lc[64][65], ls[64][65];
  const int t  = threadIdx.x;
  const int bk = blockIdx.x & 15;
  const int bd = blockIdx.x >> 4;
  const int k0 = bk * 64, d0 = bd * 64;
  const int c = t & 63;
  #pragma unroll
  for (int i = 0; i < 16; ++i) {
    const int r = (t >> 6) + i * 4;
    float a = cb[(size_t)(k0 + r) * DIMS + d0 + c];
    float s, cc; sincosf(a, &s, &cc);
    lc[r][c] = cc; ls[r][c] = s;
  }
  __syncthreads();
  ushort* T1 = (ushort*)ws;
  #pragma unroll
  for (int j = 0; j < 16; ++j) {
    const int dd = (t >> 6) + j * 4;
    T1[(size_t)((d0 + dd) * 2 + 0) * KCODES + k0 + c] = f2bf(lc[c][dd]);
    T1[(size_t)((d0 + dd) * 2 + 1) * KCODES + k0 + c] = f2bf(ls[c][dd]);
  }
}

// ---- one-time: T2g[g][j][c] build (r8-proven) ----
__global__ __launch_bounds__(256) void k_trig2(const float* __restrict__ cb,
                                               float* __restrict__ ws) {
  __shared__ float cbl[4][DIMS];         // 64 KB
  const int t = threadIdx.x;
  const int g = blockIdx.x;              // codes 4g..4g+3
  #pragma unroll
  for (int c = 0; c < 4; ++c)
    #pragma unroll
    for (int q = 0; q < 4; ++q) {
      const int off = (q * 256 + t) * 4;
      *(float4*)&cbl[c][off] = *(const float4*)&cb[(size_t)(4 * g + c) * DIMS + off];
    }
  __syncthreads();

  ushort buf[128];
  #pragma unroll
  for (int dl = 0; dl < 16; ++dl) {
    #pragma unroll
    for (int c = 0; c < 4; ++c) {
      float s, cc; sincosf(cbl[c][16 * t + dl], &s, &cc);
      buf[(2 * dl + 0) * 4 + c] = f2bf(cc);
      buf[(2 * dl + 1) * 4 + c] = f2bf(s);
    }
  }
  uint4* dst = (uint4*)((ushort*)(ws + T2_OFF) + (size_t)g * (JROWS * 4) + t * 128);
  const uint4* src = (const uint4*)buf;
  #pragma unroll
  for (int i = 0; i < 16; ++i) dst[i] = src[i];
}

// ---- one-time: est[j][b] from superposed ----
__global__ __launch_bounds__(256) void k_init(const float* __restrict__ sup,
                                              float* __restrict__ ws) {
  float* EST = ws + EST_OFF;
  const int i = blockIdx.x * 256 + threadIdx.x;   // 0..32767
  const int b = i >> 12, d = i & 4095;
  float s, c; sincosf(sup[(size_t)b * DIMS + d], &s, &c);
  EST[(2 * d + 0) * BATCH + b] = c;
  EST[(2 * d + 1) * BATCH + b] = s;
}

// ---- per-iter: fused simw + est, one REGULAR dispatch, rotating W slot ----
__global__ __launch_bounds__(512) void k_iter(float* __restrict__ ws,
                                              const int* __restrict__ nit_p,
                                              float* __restrict__ out,
                                              int it) {
  const int NI = *nit_p;
  __shared__ float Wl[BATCH * KCODES];   // est: W stage (32 KB); simw: scr[256]
  float* W = ws + WROT_OFF + (size_t)it * W_SZ;   // fresh slot each iteration
  unsigned* fgrp = (unsigned*)(ws + FLAG_OFF);
  unsigned* ffin = (unsigned*)(ws + FLAG_OFF) + FGRP_SZ;
  const int t = threadIdx.x, lane = t & 63, wv = t >> 6;
  const int bid = blockIdx.x;

  if (bid < 256) {
    // ================= simw role: 4 codes, k-split ========================
    if (it > NI) return;
    const ushort* T2  = (const ushort*)(ws + T2_OFF);
    const float*  EST = ws + EST_OFF;
    const int g = bid;
    const ushort* trow = T2 + (size_t)g * (JROWS * 4);
    float* scr = Wl;                     // 256 floats of the shared buffer

    float acc[4][BATCH];
    #pragma unroll
    for (int c = 0; c < 4; ++c)
      #pragma unroll
      for (int b = 0; b < BATCH; ++b) acc[c][b] = 0.f;

    #pragma unroll 4
    for (int i = 0; i < 16; ++i) {
      const int j = i * 512 + t;
      const float4 e0 = *(const float4*)&EST[j * BATCH + 0];
      const float4 e1 = *(const float4*)&EST[j * BATCH + 4];
      const float ev[8] = {e0.x, e0.y, e0.z, e0.w, e1.x, e1.y, e1.z, e1.w};
      const ushort4 tu = *(const ushort4*)&trow[j * 4];
      const float tc[4] = {bf2f(tu.x), bf2f(tu.y), bf2f(tu.z), bf2f(tu.w)};
      #pragma unroll
      for (int c = 0; c < 4; ++c)
        #pragma unroll
        for (int b = 0; b < BATCH; ++b)
          acc[c][b] = fmaf(tc[c], ev[b], acc[c][b]);
    }

    #pragma unroll
    for (int c = 0; c < 4; ++c)
      #pragma unroll
      for (int b = 0; b < BATCH; ++b) {
        const float s = wave_sum64(acc[c][b]);
        if (lane == 63) scr[wv * 32 + c * BATCH + b] = s;
      }
    __syncthreads();

    if (t < 32) {                        // all within wave 0
      float s = 0.f;
      #pragma unroll
      for (int w8 = 0; w8 < 8; ++w8) s += scr[w8 * 32 + t];
      const int c = t >> 3, b = t & 7;
      if (it == NI) out[b * KCODES + 4 * g + c] = s * (1.0f / (float)DIMS);
      else          W[b * KCODES + 4 * g + c] = exp2f(s * C2);  // plain store
    }
    if (it < NI) {
      // wave 0: wbl2 pushes its W stores to the LLC (r6-proven publish)
      if (t < 64) __threadfence();
      if (t == 0) {
        unsigned* grp = fgrp + (it * NGRP + (bid & (NGRP - 1))) * GSTRIDE;
        const unsigned old =
            __hip_atomic_fetch_add(grp, 1u, __ATOMIC_RELEASE,
                                   __HIP_MEMORY_SCOPE_AGENT);
        if (old == 15u)                  // 16th arrival: group leader
          __hip_atomic_fetch_add(&ffin[it * GSTRIDE], 1u, __ATOMIC_RELEASE,
                                 __HIP_MEMORY_SCOPE_AGENT);
      }
    }
  } else {
    // ================= est role: 16 dims, d-split =========================
    if (it >= NI) return;
    const ushort* T1 = (const ushort*)ws;
    float* EST = ws + EST_OFF;
    __shared__ float est_l[32 * BATCH];
    const int r0 = (bid - 256) * 32;

    if (t == 0) {
      // relaxed spin: observes LLC RMWs; slot-it lines were never in this
      // XCD's caches this dispatch -> later reads miss to the LLC.
      while (__hip_atomic_load(&ffin[it * GSTRIDE], __ATOMIC_RELAXED,
                               __HIP_MEMORY_SCOPE_AGENT) < (unsigned)NGRP)
        __builtin_amdgcn_s_sleep(1);
    }
    __syncthreads();

    #pragma unroll
    for (int j = 0; j < 4; ++j) {        // plain float4 W loads (L2-miss -> LLC)
      const int idx = (j * 512 + t) * 4;
      *(float4*)&Wl[idx] = *(const float4*)&W[idx];
    }
    __syncthreads();

    const int rw = wv * 4;
    float acc[4][BATCH];
    #pragma unroll
    for (int r = 0; r < 4; ++r)
      #pragma unroll
      for (int b = 0; b < BATCH; ++b) acc[r][b] = 0.f;

    #pragma unroll
    for (int c = 0; c < 4; ++c) {
      const int kk = c * 256 + lane * 4;
      float4 wr[BATCH];
      #pragma unroll
      for (int b = 0; b < BATCH; ++b)
        wr[b] = *(const float4*)&Wl[b * KCODES + kk];
      #pragma unroll
      for (int r = 0; r < 4; ++r) {
        const ushort4 tu = *(const ushort4*)&T1[(size_t)(r0 + rw + r) * KCODES + kk];
        const float4 tv = make_float4(bf2f(tu.x), bf2f(tu.y), bf2f(tu.z), bf2f(tu.w));
        #pragma unroll
        for (int b = 0; b < BATCH; ++b) {
          acc[r][b] = fmaf(wr[b].x, tv.x, acc[r][b]);
          acc[r][b] = fmaf(wr[b].y, tv.y, acc[r][b]);
          acc[r][b] = fmaf(wr[b].z, tv.z, acc[r][b]);
          acc[r][b] = fmaf(wr[b].w, tv.w, acc[r][b]);
        }
      }
    }
    #pragma unroll
    for (int r = 0; r < 4; ++r)
      #pragma unroll
      for (int b = 0; b < BATCH; ++b) {
        const float s = wave_sum64(acc[r][b]);
        if (lane == 63) est_l[(rw + r) * BATCH + b] = s;
      }
    __syncthreads();

    if (t < 128) {                       // normalize: (re,im)/|z|
      const int dl = t >> 3, b = t & 7;
      const float re = est_l[(2 * dl + 0) * BATCH + b];
      const float im = est_l[(2 * dl + 1) * BATCH + b];
      const float n2 = fmaf(re, re, im * im);
      float ec, es;
      if (n2 > 0.f) {
        const float inv = rsqrtf(n2);
        ec = re * inv; es = im * inv;
      } else { ec = 1.f; es = 0.f; }     // atan2(0,0) = 0
      est_l[(2 * dl + 0) * BATCH + b] = ec;
      est_l[(2 * dl + 1) * BATCH + b] = es;
    }
    __syncthreads();

    if (t < 256) EST[r0 * BATCH + t] = est_l[t];   // plain store; next
                                                   // dispatch boundary = release
  }
}

extern "C" void kernel_launch(void* const* d_in, const int* in_sizes, int n_in,
                              void* d_out, int out_size, void* d_ws, size_t ws_size,
                              hipStream_t stream) {
  const float* sup = (const float*)d_in[0];
  const float* cbk = (const float*)d_in[1];
  const int*   nit = (const int*)d_in[2];
  float* outp = (float*)d_out;
  float* ws   = (float*)d_ws;

  // zero group + final counters (graph-capture safe, once per launch)
  hipMemsetAsync((char*)d_ws + (size_t)FLAG_OFF * sizeof(float), 0,
                 (size_t)(FGRP_SZ + FFIN_SZ) * sizeof(unsigned), stream);

  hipLaunchKernelGGL(k_trig,  dim3(1024), dim3(256), 0, stream, cbk, ws);
  hipLaunchKernelGGL(k_trig2, dim3(256),  dim3(256), 0, stream, cbk, ws);
  hipLaunchKernelGGL(k_init,  dim3(128),  dim3(256), 0, stream, sup, ws);

  for (int it = 0; it <= NITER_MAX; ++it) {   // it==NITER_MAX: out pass
    hipLaunchKernelGGL(k_iter, dim3(512), dim3(512), 0, stream,
                       ws, nit, outp, it);
  }
}

// Round 14
// 728.056 us; speedup vs baseline: 1.5757x; 1.5757x over previous
//
#include <hip/hip_runtime.h>
#include <hip/hip_fp16.h>
#include <math.h>

// Round 14 = Round 7 verbatim (best verified: 731 µs, absmax 4.88e-4).
// Structure: 2 kernels/iteration on a graph-replayed stream (kernel boundary
// = the cheapest cross-XCD sync on MI355X, ~4.7 µs; measured cheaper than
// in-kernel flag handoff (~10 µs, r13) and grid barriers (~10 µs, r6)).
//   k_wexp  : chunked all-reduce of fp16 partials P[256][8][1024] -> W =
//             exp2(c2*S) (unnormalized softmax: atan2 direction is
//             scale-invariant, Z cancels). 256 blocks, thread-per-slice,
//             DPP wave reduce.
//   k_fused : per 16-dim slice (block bid, stable bid->XCD affinity keeps its
//             64 KB bf16 T1 slice L2-hot across all 50 iters): W.T1 est-GEMM
//             (8 waves x 4 rows, DPP reduce) -> normalize est in LDS
//             (cos=re/|z|, sin=im/|z|; no atan2) -> next-iter sims partials
//             -> fp16 P store.
// T1[row=d*2+cs][k] bf16 (16 MB), k-contiguous: coalesced in both phases.

#define KCODES 1024
#define DIMS   4096
#define BATCH  8
#define NITER_MAX 50          // device-side guard handles *nit_p < NITER_MAX
#define NSLICE 256            // P slices (16 dims each)

// ws layout (float offsets), ~21 MB total
#define T1_SZF   (DIMS * 2 * KCODES / 2)       // bf16 T1: 4,194,304 f32 slots
#define EST_OFF  (T1_SZF)
#define EST_SZ   (DIMS * 2 * BATCH)            // est[row][b] f32 (one-time)
#define W_OFF    (EST_OFF + EST_SZ)
#define W_SZ     (BATCH * KCODES)
#define P_OFF    (W_OFF + W_SZ)                // fp16 partials [ds][b][k]

#define C2 (0.00244140625f * 1.4426950408889634f)   // (10/4096)*log2(e)

// ---- bf16 helpers ----
__device__ __forceinline__ ushort f2bf(float x) {
  unsigned u = __float_as_uint(x);
  return (ushort)((u + 0x7FFFu + ((u >> 16) & 1u)) >> 16);   // RNE
}
__device__ __forceinline__ float bf2f(ushort u) {
  return __uint_as_float(((unsigned)u) << 16);
}

// ---- DPP wave64 sum: result valid in lane 63 ----
template <int CTRL>
__device__ __forceinline__ float dpp_add(float x) {
  int v = __builtin_amdgcn_update_dpp(0, __float_as_int(x), CTRL, 0xF, 0xF, false);
  return x + __int_as_float(v);
}
__device__ __forceinline__ float wave_sum64(float x) {
  x = dpp_add<0x111>(x);   // row_shr:1
  x = dpp_add<0x112>(x);   // row_shr:2
  x = dpp_add<0x114>(x);   // row_shr:4
  x = dpp_add<0x118>(x);   // row_shr:8
  x = dpp_add<0x142>(x);   // row_bcast:15
  x = dpp_add<0x143>(x);   // row_bcast:31
  return x;                // lane 63 = sum of all 64 lanes
}

// ---- one-time: codebook angles -> bf16 T1[(d*2+cs)][k] via LDS transpose ----
__global__ __launch_bounds__(256) void k_trig(const float* __restrict__ cb,
                                              float* __restrict__ ws) {
  __shared__ float lc[64][65], ls[64][65];
  const int t  = threadIdx.x;
  const int bk = blockIdx.x & 15;        // 16 k-tiles
  const int bd = blockIdx.x >> 4;        // 64 d-tiles
  const int k0 = bk * 64, d0 = bd * 64;
  const int c = t & 63;
  #pragma unroll
  for (int i = 0; i < 16; ++i) {
    const int r = (t >> 6) + i * 4;
    float a = cb[(size_t)(k0 + r) * DIMS + d0 + c];
    float s, cc; sincosf(a, &s, &cc);
    lc[r][c] = cc; ls[r][c] = s;
  }
  __syncthreads();
  ushort* T1 = (ushort*)ws;
  #pragma unroll
  for (int j = 0; j < 16; ++j) {
    const int dd = (t >> 6) + j * 4;
    T1[(size_t)((d0 + dd) * 2 + 0) * KCODES + k0 + c] = f2bf(lc[c][dd]);
    T1[(size_t)((d0 + dd) * 2 + 1) * KCODES + k0 + c] = f2bf(ls[c][dd]);
  }
}

// ---- one-time: est init from superposed (f32, read only by k_sims0) ----
__global__ __launch_bounds__(256) void k_init(const float* __restrict__ sup,
                                              float* __restrict__ ws) {
  float* EST = ws + EST_OFF;
  const int i = blockIdx.x * 256 + threadIdx.x;   // 0..32767
  const int b = i >> 12, d = i & 4095;
  float s, c; sincosf(sup[(size_t)b * DIMS + d], &s, &c);
  EST[(d * 2 + 0) * BATCH + b] = c;
  EST[(d * 2 + 1) * BATCH + b] = s;
}

// ---- one-time: initial partial sims from EST ----
__global__ __launch_bounds__(256) void k_sims0(float* __restrict__ ws) {
  const ushort* T1  = (const ushort*)ws;
  const float*  EST = ws + EST_OFF;
  __half* P = (__half*)(ws + P_OFF);
  const int t  = threadIdx.x;
  const int ds = blockIdx.x;
  const int r0 = ds * 32;
  const int k4 = t * 4;

  float4 acc[BATCH];
  #pragma unroll
  for (int b = 0; b < BATCH; ++b) acc[b] = make_float4(0.f, 0.f, 0.f, 0.f);

  #pragma unroll 8
  for (int r = 0; r < 32; ++r) {
    const int row = r0 + r;
    const ushort4 tu = *(const ushort4*)&T1[(size_t)row * KCODES + k4];
    const float4 tv = make_float4(bf2f(tu.x), bf2f(tu.y), bf2f(tu.z), bf2f(tu.w));
    const float4 e0 = *(const float4*)&EST[row * BATCH + 0];
    const float4 e1 = *(const float4*)&EST[row * BATCH + 4];
    const float ev[8] = {e0.x, e0.y, e0.z, e0.w, e1.x, e1.y, e1.z, e1.w};
    #pragma unroll
    for (int b = 0; b < BATCH; ++b) {
      acc[b].x = fmaf(ev[b], tv.x, acc[b].x);
      acc[b].y = fmaf(ev[b], tv.y, acc[b].y);
      acc[b].z = fmaf(ev[b], tv.z, acc[b].z);
      acc[b].w = fmaf(ev[b], tv.w, acc[b].w);
    }
  }
  #pragma unroll
  for (int b = 0; b < BATCH; ++b) {
    __half* pp = &P[(size_t)ds * (BATCH * KCODES) + b * KCODES + k4];
    *(__half2*)(pp + 0) = __floats2half2_rn(acc[b].x, acc[b].y);
    *(__half2*)(pp + 2) = __floats2half2_rn(acc[b].z, acc[b].w);
  }
}

// ---- per-iter 1: chunked P all-reduce -> W = exp2(c2*S) (unnormalized) ----
// 256 blocks x 256 thr; block = (b2, k0..k0+31) chunk; thread = one slice.
__global__ __launch_bounds__(256) void k_wexp(float* __restrict__ ws,
                                              const int* __restrict__ nit_p,
                                              int it) {
  if (it >= *nit_p) return;
  const __half* P = (const __half*)(ws + P_OFF);
  float* W = ws + W_OFF;
  __shared__ float scr[128];
  const int t = threadIdx.x, lane = t & 63, wv = t >> 6;
  const int b2 = blockIdx.x >> 5;
  const int k0 = (blockIdx.x & 31) * 32;

  float4 raw[4];
  const float4* p4 =
      (const float4*)(P + (size_t)t * (BATCH * KCODES) + b2 * KCODES + k0);
  raw[0] = p4[0]; raw[1] = p4[1]; raw[2] = p4[2]; raw[3] = p4[3];
  const __half2* h2 = (const __half2*)raw;
  #pragma unroll
  for (int kk = 0; kk < 16; ++kk) {
    const float2 f2 = __half22float2(h2[kk]);
    const float s0 = wave_sum64(f2.x);
    const float s1 = wave_sum64(f2.y);
    if (lane == 63) {
      scr[wv * 32 + 2 * kk + 0] = s0;
      scr[wv * 32 + 2 * kk + 1] = s1;
    }
  }
  __syncthreads();
  if (t < 32) {
    const float s = scr[t] + scr[32 + t] + scr[64 + t] + scr[96 + t];
    W[b2 * KCODES + k0 + t] = exp2f(s * C2);
  }
}

// ---- per-iter 2: W.T1 est-GEMM -> normalize (LDS) -> next sims -> P ----
// 256 blocks x 512 thr; block = 32 T1 rows (16 dims), L2-hot via bid affinity.
__global__ __launch_bounds__(512) void k_fused(float* __restrict__ ws,
                                               const int* __restrict__ nit_p,
                                               int it) {
  if (it >= *nit_p) return;
  const ushort* T1 = (const ushort*)ws;
  const float*  Wg = ws + W_OFF;
  __half* P = (__half*)(ws + P_OFF);

  __shared__ float smem[BATCH * KCODES];   // 32 KB: W, then sims half-combine
  __shared__ float est_l[32 * BATCH];      // raw re/im -> normalized est

  const int t = threadIdx.x, lane = t & 63, wv = t >> 6;
  const int r0 = blockIdx.x * 32;

  #pragma unroll
  for (int j = 0; j < 4; ++j) {            // load full W into LDS
    const int idx = (j * 512 + t) * 4;
    *(float4*)&smem[idx] = *(const float4*)&Wg[idx];
  }
  __syncthreads();

  // phase 1: wave wv owns rows rw..rw+3; re/im = W . T1row
  const int rw = wv * 4;                   // local row base
  float acc[4][BATCH];
  #pragma unroll
  for (int r = 0; r < 4; ++r)
    #pragma unroll
    for (int b = 0; b < BATCH; ++b) acc[r][b] = 0.f;

  #pragma unroll
  for (int c = 0; c < 4; ++c) {
    const int kk = c * 256 + lane * 4;
    float4 wr[BATCH];
    #pragma unroll
    for (int b = 0; b < BATCH; ++b)
      wr[b] = *(const float4*)&smem[b * KCODES + kk];
    #pragma unroll
    for (int r = 0; r < 4; ++r) {
      const ushort4 tu = *(const ushort4*)&T1[(size_t)(r0 + rw + r) * KCODES + kk];
      const float4 tv = make_float4(bf2f(tu.x), bf2f(tu.y), bf2f(tu.z), bf2f(tu.w));
      #pragma unroll
      for (int b = 0; b < BATCH; ++b) {
        acc[r][b] = fmaf(wr[b].x, tv.x, acc[r][b]);
        acc[r][b] = fmaf(wr[b].y, tv.y, acc[r][b]);
        acc[r][b] = fmaf(wr[b].z, tv.z, acc[r][b]);
        acc[r][b] = fmaf(wr[b].w, tv.w, acc[r][b]);
      }
    }
  }
  #pragma unroll
  for (int r = 0; r < 4; ++r)
    #pragma unroll
    for (int b = 0; b < BATCH; ++b) {
      const float s = wave_sum64(acc[r][b]);
      if (lane == 63) est_l[(rw + r) * BATCH + b] = s;
    }
  __syncthreads();

  if (t < 128) {                           // normalize est in LDS
    const int dl = t >> 3, b = t & 7;
    const float re = est_l[(2 * dl + 0) * BATCH + b];
    const float im = est_l[(2 * dl + 1) * BATCH + b];
    const float n2 = fmaf(re, re, im * im);
    float ec, es;
    if (n2 > 0.f) {
      const float inv = rsqrtf(n2);
      ec = re * inv; es = im * inv;
    } else { ec = 1.f; es = 0.f; }         // atan2(0,0) = 0
    est_l[(2 * dl + 0) * BATCH + b] = ec;
    est_l[(2 * dl + 1) * BATCH + b] = es;
  }
  __syncthreads();

  // phase 2: next-iter sims partials for this slice (T1 rows L2-hot)
  const int half = t >> 8, tk = t & 255, k4 = tk * 4;
  const int rb = half * 16;
  float4 a[BATCH];
  #pragma unroll
  for (int b = 0; b < BATCH; ++b) a[b] = make_float4(0.f, 0.f, 0.f, 0.f);

  #pragma unroll
  for (int r = 0; r < 16; ++r) {
    const int lr = rb + r;
    const ushort4 tu = *(const ushort4*)&T1[(size_t)(r0 + lr) * KCODES + k4];
    const float4 tv = make_float4(bf2f(tu.x), bf2f(tu.y), bf2f(tu.z), bf2f(tu.w));
    const float4 e0 = *(const float4*)&est_l[lr * BATCH + 0];
    const float4 e1 = *(const float4*)&est_l[lr * BATCH + 4];
    const float ev[8] = {e0.x, e0.y, e0.z, e0.w, e1.x, e1.y, e1.z, e1.w};
    #pragma unroll
    for (int b = 0; b < BATCH; ++b) {
      a[b].x = fmaf(ev[b], tv.x, a[b].x);
      a[b].y = fmaf(ev[b], tv.y, a[b].y);
      a[b].z = fmaf(ev[b], tv.z, a[b].z);
      a[b].w = fmaf(ev[b], tv.w, a[b].w);
    }
  }
  if (half == 1) {
    #pragma unroll
    for (int b = 0; b < BATCH; ++b)
      *(float4*)&smem[(b * 256 + tk) * 4] = a[b];   // 16B lane stride: no conflicts
  }
  __syncthreads();
  if (half == 0) {
    #pragma unroll
    for (int b = 0; b < BATCH; ++b) {
      const float4 o = *(const float4*)&smem[(b * 256 + tk) * 4];
      __half* pp = &P[(size_t)blockIdx.x * (BATCH * KCODES) + b * KCODES + k4];
      *(__half2*)(pp + 0) = __floats2half2_rn(a[b].x + o.x, a[b].y + o.y);
      *(__half2*)(pp + 2) = __floats2half2_rn(a[b].z + o.z, a[b].w + o.w);
    }
  }
}

// ---- epilogue: out = (sum of 256 partials) / DIMS (chunked like k_wexp) ----
__global__ __launch_bounds__(256) void k_out(const float* __restrict__ ws,
                                             float* __restrict__ out) {
  const __half* P = (const __half*)(ws + P_OFF);
  __shared__ float scr[128];
  const int t = threadIdx.x, lane = t & 63, wv = t >> 6;
  const int b2 = blockIdx.x >> 5;
  const int k0 = (blockIdx.x & 31) * 32;

  float4 raw[4];
  const float4* p4 =
      (const float4*)(P + (size_t)t * (BATCH * KCODES) + b2 * KCODES + k0);
  raw[0] = p4[0]; raw[1] = p4[1]; raw[2] = p4[2]; raw[3] = p4[3];
  const __half2* h2 = (const __half2*)raw;
  #pragma unroll
  for (int kk = 0; kk < 16; ++kk) {
    const float2 f2 = __half22float2(h2[kk]);
    const float s0 = wave_sum64(f2.x);
    const float s1 = wave_sum64(f2.y);
    if (lane == 63) {
      scr[wv * 32 + 2 * kk + 0] = s0;
      scr[wv * 32 + 2 * kk + 1] = s1;
    }
  }
  __syncthreads();
  if (t < 32) {
    const float s = scr[t] + scr[32 + t] + scr[64 + t] + scr[96 + t];
    out[b2 * KCODES + k0 + t] = s * (1.0f / (float)DIMS);
  }
}

extern "C" void kernel_launch(void* const* d_in, const int* in_sizes, int n_in,
                              void* d_out, int out_size, void* d_ws, size_t ws_size,
                              hipStream_t stream) {
  const float* sup = (const float*)d_in[0];
  const float* cbk = (const float*)d_in[1];
  const int*   nit = (const int*)d_in[2];
  float* outp = (float*)d_out;
  float* ws   = (float*)d_ws;

  hipLaunchKernelGGL(k_trig,  dim3(1024), dim3(256), 0, stream, cbk, ws);
  hipLaunchKernelGGL(k_init,  dim3(128),  dim3(256), 0, stream, sup, ws);
  hipLaunchKernelGGL(k_sims0, dim3(256),  dim3(256), 0, stream, ws);

  for (int it = 0; it < NITER_MAX; ++it) {
    hipLaunchKernelGGL(k_wexp,  dim3(256), dim3(256), 0, stream, ws, nit, it);
    hipLaunchKernelGGL(k_fused, dim3(256), dim3(512), 0, stream, ws, nit, it);
  }
  hipLaunchKernelGGL(k_out, dim3(256), dim3(256), 0, stream, ws, outp);
}